// Round 5
// baseline (419.119 us; speedup 1.0000x reference)
//
#include <hip/hip_runtime.h>
#include <math.h>

// Problem: N=262144, D=128, C=1024. fp32 embeddings, int32/int64 labels.
// Identity: per_class = (count - ||sum_{i in c} norm(emb_i)||) / count.
// NO sort, NO gather: streaming segment-sum with LDS [1024 classes][16 dims]
// privatized accumulators (64 KB) and hardware ds_add_f32 atomics.
// Dispatches: memset(528KB) + norm + accum(8 dim-groups x 32 chunks) + finalize.
#define NUM_CLASSES 1024
#define AS3 __attribute__((address_space(3)))

__device__ __forceinline__ int detect_mode32(const int* __restrict__ l) {
    // uniform scalar loads; 1 -> labels are int32, 0 -> int64 (read low words)
    return (l[1] | l[3] | l[5] | l[7] | l[9] | l[11] | l[13] | l[15]) != 0;
}

__device__ __forceinline__ int get_label(const int* __restrict__ l, int i, int mode32) {
    return l[mode32 ? i : (i << 1)] & (NUM_CLASSES - 1);
}

__device__ __forceinline__ float sumsq8(const float4 a, const float4 b) {
    return a.x*a.x + a.y*a.y + a.z*a.z + a.w*a.w
         + b.x*b.x + b.y*b.y + b.z*b.z + b.w*b.w;
}

__device__ __forceinline__ float red16(float sq) {
    sq += __shfl_xor(sq, 1, 64);
    sq += __shfl_xor(sq, 2, 64);
    sq += __shfl_xor(sq, 4, 64);
    sq += __shfl_xor(sq, 8, 64);
    return sq;
}

// Hardware LDS float atomic (fire-and-forget, no CAS loop). Address is the
// 32-bit LDS byte offset (ptrtoint of an addrspace(3) pointer).
__device__ __forceinline__ void ds_addf(float* p, float v) {
    asm volatile("ds_add_f32 %0, %1"
                 :: "v"((unsigned)(unsigned long long)(AS3 float*)p), "v"(v));
}

// ---------------- K1: inv_norm per sample (pure coalesced stream) ----------------
// 16 lanes/row (2x float4/lane); each 16-lane group runs 4 rows in flight,
// 2 quad-iters -> 128 rows/block. Grid = N/128 = 2048 blocks (32 waves/CU).
__global__ __launch_bounds__(256, 6) void norm_kernel(
        const float* __restrict__ emb, int n, float* __restrict__ inv_norm) {
    const int wave = threadIdx.x >> 6, lane = threadIdx.x & 63;
    const int g = lane >> 4, sub = lane & 15;
    const int grp = wave * 4 + g;          // 0..15
    const float4* emb4 = (const float4*)emb;
    const int base = blockIdx.x * 128;
    if (base + 128 <= n) {
        #pragma unroll
        for (int q = 0; q < 2; ++q) {
            const int r = base + q * 64 + grp;
            const float4* p0 = emb4 + (size_t)(r     ) * 32;
            const float4* p1 = emb4 + (size_t)(r + 16) * 32;
            const float4* p2 = emb4 + (size_t)(r + 32) * 32;
            const float4* p3 = emb4 + (size_t)(r + 48) * 32;
            float4 a0 = p0[sub], a1 = p0[sub + 16];
            float4 b0 = p1[sub], b1 = p1[sub + 16];
            float4 c0 = p2[sub], c1 = p2[sub + 16];
            float4 d0 = p3[sub], d1 = p3[sub + 16];
            float sa = red16(sumsq8(a0, a1));
            float sb = red16(sumsq8(b0, b1));
            float sc = red16(sumsq8(c0, c1));
            float sd = red16(sumsq8(d0, d1));
            if (sub == 0) {
                inv_norm[r]      = 1.0f / fmaxf(sqrtf(sa), 1e-12f);
                inv_norm[r + 16] = 1.0f / fmaxf(sqrtf(sb), 1e-12f);
                inv_norm[r + 32] = 1.0f / fmaxf(sqrtf(sc), 1e-12f);
                inv_norm[r + 48] = 1.0f / fmaxf(sqrtf(sd), 1e-12f);
            }
        }
    } else {
        for (int r = base + grp; r < n; r += 16) {   // group-uniform exit
            const float4* p = emb4 + (size_t)r * 32;
            float4 a0 = p[sub], a1 = p[sub + 16];
            float s = red16(sumsq8(a0, a1));
            if (sub == 0) inv_norm[r] = 1.0f / fmaxf(sqrtf(s), 1e-12f);
        }
    }
}

// ---------------- K2: streaming segment-sum, dim-sliced ----------------
// bx = dg*32 + chunk. Block reads ONLY dims [dg*16, dg*16+16) of its 8192-
// sample chunk (disjoint 64-B segments across blocks -> 1x total traffic).
// LDS [1024][16] f32 = 64 KB; ds_add_f32 accumulation; dg==0 blocks also
// build the class histogram. Flush: global HW f32 atomics into sums[1024][128].
#define K2_THREADS 1024
__global__ __launch_bounds__(K2_THREADS, 4) void accum_kernel(
        const float* __restrict__ emb, const int* __restrict__ labels, int n,
        const float* __restrict__ inv_norm, float* __restrict__ sums,
        int* __restrict__ counts) {
    __shared__ float lds[NUM_CLASSES * 16];       // 64 KB
    const int mode32 = detect_mode32(labels);
    const int dg    = blockIdx.x >> 5;            // 0..7
    const int chunk = blockIdx.x & 31;            // 0..31
    const int csz   = (n + 31) >> 5;
    const int cbase = chunk * csz;
    const int cend  = min(n, cbase + csz);

    if (dg == 0) {   // histogram pre-phase (block-uniform branch)
        int* hi = (int*)lds;
        for (int t = threadIdx.x; t < NUM_CLASSES; t += K2_THREADS) hi[t] = 0;
        __syncthreads();
        for (int i = cbase + threadIdx.x; i < cend; i += K2_THREADS)
            atomicAdd(&hi[get_label(labels, i, mode32)], 1);
        __syncthreads();
        for (int t = threadIdx.x; t < NUM_CLASSES; t += K2_THREADS) {
            int v = hi[t];
            if (v) atomicAdd(&counts[t], v);
        }
        __syncthreads();
    }

    float4* l4 = (float4*)lds;
    for (int t = threadIdx.x; t < NUM_CLASSES * 4; t += K2_THREADS)
        l4[t] = make_float4(0.f, 0.f, 0.f, 0.f);
    __syncthreads();

    // wave = 16 samples/iter: lane -> (slot = lane>>2, f4 = lane&3).
    // Load float4 (16 B/lane, 1 KB/wave-instr); 4 ds_add_f32 per lane.
    const int wave = threadIdx.x >> 6;
    const int slot = (threadIdx.x & 63) >> 2;     // 0..15
    const int f4   = threadIdx.x & 3;             // float4 index in 16-dim slice
    const int soff = wave * 16 + slot;            // 0..255
    const float* ebase = emb + dg * 16 + f4 * 4;
    const int nsamp = cend - cbase;
    const int TF = nsamp >> 8;                    // full 256-sample iters
    #pragma unroll 4
    for (int t = 0; t < TF; ++t) {
        const int i = cbase + t * 256 + soff;
        float4 v = *(const float4*)(ebase + (size_t)i * 128);
        const int c = get_label(labels, i, mode32);
        const float w = inv_norm[i];
        float* row = &lds[(c << 4) | (f4 << 2)];
        ds_addf(row + 0, v.x * w);
        ds_addf(row + 1, v.y * w);
        ds_addf(row + 2, v.z * w);
        ds_addf(row + 3, v.w * w);
    }
    for (int i = cbase + TF * 256 + soff; i < cend; i += 256) {   // tail
        float4 v = *(const float4*)(ebase + (size_t)i * 128);
        const int c = get_label(labels, i, mode32);
        const float w = inv_norm[i];
        float* row = &lds[(c << 4) | (f4 << 2)];
        ds_addf(row + 0, v.x * w);
        ds_addf(row + 1, v.y * w);
        ds_addf(row + 2, v.z * w);
        ds_addf(row + 3, v.w * w);
    }
    asm volatile("s_waitcnt lgkmcnt(0)" ::: "memory");  // drain asm ds ops
    __syncthreads();

    // Flush 64 KB -> sums[c*128 + dg*16 + dd] via HW global f32 atomics.
    for (int t = threadIdx.x; t < NUM_CLASSES * 16; t += K2_THREADS) {
        const int c = t >> 4, dd = t & 15;
        unsafeAtomicAdd(&sums[(size_t)c * 128 + dg * 16 + dd], lds[t]);
    }
}

// ---------------- K3: per-class norm -> loss, ticket finalize ----------------
__global__ __launch_bounds__(128) void finalize_kernel(
        const float* __restrict__ sums, const int* __restrict__ counts,
        float* __restrict__ accum, int* __restrict__ ticket,
        float* __restrict__ out) {
    const int c = blockIdx.x;
    const float t = sums[(size_t)c * 128 + threadIdx.x];
    __shared__ float red[128];
    red[threadIdx.x] = t * t;
    __syncthreads();
    if (threadIdx.x < 64) {
        float x = red[threadIdx.x] + red[threadIdx.x + 64];
        #pragma unroll
        for (int off = 32; off; off >>= 1) x += __shfl_xor(x, off, 64);
        if (threadIdx.x == 0) {
            const int count = counts[c];
            if (count >= 2) {
                float per_class = ((float)count - sqrtf(x)) / (float)count;
                atomicAdd(&accum[0], per_class);
                atomicAdd(&accum[1], 1.0f);
            }
            __threadfence();
            int old = atomicAdd(ticket, 1);
            if (old == (int)gridDim.x - 1) {
                float ls = atomicAdd(&accum[0], 0.0f);   // device-scope reads
                float nv = atomicAdd(&accum[1], 0.0f);
                out[0] = (nv > 0.0f) ? (ls / nv) : 0.0f;
            }
        }
    }
}

extern "C" void kernel_launch(void* const* d_in, const int* in_sizes, int n_in,
                              void* d_out, int out_size, void* d_ws, size_t ws_size,
                              hipStream_t stream) {
    const float* emb  = (const float*)d_in[0];   // fp32, N x 128
    const int* labels = (const int*)d_in[1];     // int32 (int64 handled inline)
    int n = in_sizes[1];                         // 262144 samples

    // Workspace layout (~1.6 MB)
    char* ws = (char*)d_ws;
    float* sums     = (float*)(ws);              // 1024*128 f32 = 512 KB
    int*   counts   = (int*)(ws + 524288);       // 1024 ints
    float* accum    = (float*)(ws + 528384);     // 2 floats
    int*   ticket   = (int*)(ws + 528392);       // 1 int
    float* inv_norm = (float*)(ws + 532480);     // n floats (1 MB)

    hipMemsetAsync(ws, 0, 528396, stream);       // sums/counts/accum/ticket

    norm_kernel<<<(n + 127) / 128, 256, 0, stream>>>(emb, n, inv_norm);
    accum_kernel<<<256, K2_THREADS, 0, stream>>>(emb, labels, n, inv_norm,
                                                 sums, counts);
    finalize_kernel<<<NUM_CLASSES, 128, 0, stream>>>(sums, counts, accum,
                                                     ticket, (float*)d_out);
}

// Round 6
// 248.600 us; speedup vs baseline: 1.6859x; 1.6859x over previous
//
#include <hip/hip_runtime.h>
#include <math.h>

// Problem constants: N=262144, D=128, C=1024.
// R2 sorted-gather pipeline (best: 249us) with class_sum rebuilt around
// __builtin_amdgcn_global_load_lds + counted vmcnt (T3/T4): per-wave
// triple-buffered 4-row batches staged async into LDS — the compiler cannot
// collapse this pipeline (no destination VGPRs). Row indices live in LDS so
// index fetches never enter the vmcnt queue.
#define NUM_CLASSES 1024
#define HIST_CHUNK 2048            // samples per hist/scatter block
#define NB 128                     // number of hist/scatter blocks (N/HIST_CHUNK)
#define WPB 8                      // waves per class_sum block

__device__ __forceinline__ int detect_mode32(const int* __restrict__ l) {
    // uniform scalar loads; 1 -> labels are int32, 0 -> int64 (read low words)
    return (l[1] | l[3] | l[5] | l[7] | l[9] | l[11] | l[13] | l[15]) != 0;
}

__device__ __forceinline__ int get_label(const int* __restrict__ l, int i, int mode32) {
    return l[mode32 ? i : (i << 1)] & (NUM_CLASSES - 1);
}

// ---------------- Kernel 1: per-block partial histograms (transposed out) ----------------
__global__ void hist_kernel(const int* __restrict__ labels, int n,
                            int* __restrict__ pT) {        // [C][NB]
    __shared__ int h[NUM_CLASSES];
    const int mode32 = detect_mode32(labels);
    for (int i = threadIdx.x; i < NUM_CLASSES; i += blockDim.x) h[i] = 0;
    __syncthreads();
    const int base = blockIdx.x * HIST_CHUNK;
    for (int k = threadIdx.x; k < HIST_CHUNK; k += blockDim.x) {
        int i = base + k;
        if (i < n) atomicAdd(&h[get_label(labels, i, mode32)], 1);
    }
    __syncthreads();
    for (int c = threadIdx.x; c < NUM_CLASSES; c += blockDim.x)
        pT[c * NB + blockIdx.x] = h[c];
}

// ---------------- Kernel 2a: per-class prefix along blocks (wave per class) ----------------
__global__ __launch_bounds__(512) void scanA_kernel(int* __restrict__ pT,
                                                    int* __restrict__ totals) {
    const int wave = threadIdx.x >> 6;
    const int lane = threadIdx.x & 63;
    const int c = blockIdx.x * 8 + wave;        // 128 blocks x 8 waves = 1024
    int* p = pT + c * NB;
    const int v0 = p[2 * lane];
    const int v1 = p[2 * lane + 1];
    int s = v0 + v1;
    #pragma unroll
    for (int d = 1; d < 64; d <<= 1) {
        int t = __shfl_up(s, d, 64);
        if (lane >= d) s += t;
    }
    const int base = s - v0 - v1;               // exclusive prefix before this pair
    p[2 * lane]     = base;
    p[2 * lane + 1] = base + v0;
    if (lane == 63) totals[c] = s;
}

// ---------------- Kernel 2b: cross-class exclusive scan (1 block) ----------------
__global__ void scanB_kernel(const int* __restrict__ totals,
                             int* __restrict__ offsets,
                             int* __restrict__ counts,
                             float* __restrict__ accum,
                             int* __restrict__ ticket) {
    __shared__ int tmp[NUM_CLASSES];
    const int c = threadIdx.x;                  // blockDim.x == 1024
    const int v = totals[c];
    tmp[c] = v;
    __syncthreads();
    for (int off = 1; off < NUM_CLASSES; off <<= 1) {
        int add = (c >= off) ? tmp[c - off] : 0;
        __syncthreads();
        tmp[c] += add;
        __syncthreads();
    }
    offsets[c] = tmp[c] - v;
    counts[c]  = v;
    if (c == 0) { accum[0] = 0.0f; accum[1] = 0.0f; *ticket = 0; }
}

// ---------------- Kernel 3: scatter via LDS cursors (no global atomics) ----------------
__global__ void scatter_kernel(const int* __restrict__ labels, int n,
                               const int* __restrict__ pT,
                               const int* __restrict__ offsets,
                               int* __restrict__ sorted) {
    __shared__ int cur[NUM_CLASSES];
    const int mode32 = detect_mode32(labels);
    for (int c = threadIdx.x; c < NUM_CLASSES; c += blockDim.x)
        cur[c] = offsets[c] + pT[c * NB + blockIdx.x];
    __syncthreads();
    const int base = blockIdx.x * HIST_CHUNK;
    for (int k = threadIdx.x; k < HIST_CHUNK; k += blockDim.x) {
        int i = base + k;
        if (i < n) {
            int pos = atomicAdd(&cur[get_label(labels, i, mode32)], 1);  // LDS atomic
            sorted[pos] = i;
        }
    }
}

// ---------------- Kernel 4: async-staged gather + per-class loss ----------------
__device__ __forceinline__ float sumsq8(const float4 a, const float4 b) {
    return a.x*a.x + a.y*a.y + a.z*a.z + a.w*a.w
         + b.x*b.x + b.y*b.y + b.z*b.z + b.w*b.w;
}

__device__ __forceinline__ float red16(float sq) {
    sq += __shfl_xor(sq, 1, 64);
    sq += __shfl_xor(sq, 2, 64);
    sq += __shfl_xor(sq, 4, 64);
    sq += __shfl_xor(sq, 8, 64);
    return sq;
}

// Stage one batch (4 rows x 512 B = 2 KB) into LDS buffer `buf`.
// Lane l writes LDS slot l (HW: uniform base + lane*16); the content for slot
// l is row/chunk s' = l ^ (l>>3) (involution) so that the consume-side read
// slot t1 = s ^ (s>>3) is bank-conflict-free. Global source is per-lane.
__device__ __forceinline__ void stage_batch(
        const float* __restrict__ emb, const int* __restrict__ ids_lds,
        const int* __restrict__ sorted_g, int cached, int start,
        int batch, int count, int srow, int schunk, char* buf) {
    const int rid = (batch << 2) + srow;
    const int rc  = (rid < count) ? rid : 0;            // clamp to a safe row
    const int idx = cached ? ids_lds[rc] : sorted_g[start + rc];
    const char* gp = (const char*)(emb + (size_t)idx * 128) + (schunk << 4);
    __builtin_amdgcn_global_load_lds(
        (const __attribute__((address_space(1))) void*)gp,
        (__attribute__((address_space(3))) void*)buf, 16, 0, 0);
    __builtin_amdgcn_global_load_lds(
        (const __attribute__((address_space(1))) void*)(gp + 256),
        (__attribute__((address_space(3))) void*)(buf + 1024), 16, 0, 0);
}

// One block (8 waves) per class. Wave w owns batches w, w+8, w+16, ... of 4
// rows each; 3 LDS buffers per wave, depth-3 async pipeline with counted
// vmcnt(4). Group g (16 lanes) reduces row g of each batch (sumsq -> rsqrt ->
// FMA accumulate; order deterministic per accumulator).
__global__ __launch_bounds__(512, 4) void class_sum_kernel(
        const float* __restrict__ emb,      // N x 128 fp32
        const int* __restrict__ sorted,
        const int* __restrict__ offsets,
        const int* __restrict__ counts,
        float* __restrict__ accum,          // [0]=loss_sum, [1]=n_valid
        int* __restrict__ ticket,
        float* __restrict__ out) {
    __shared__ __align__(16) char smem[51200];   // 48K stage + 2K ids + 1.2K pad
    const int c     = blockIdx.x;
    const int start = offsets[c];
    const int count = counts[c];
    const int wave  = threadIdx.x >> 6;
    const int lane  = threadIdx.x & 63;
    const int g     = lane >> 4;
    const int sub   = lane & 15;

    int*  ids   = (int*)(smem + 49152);          // up to 512 cached indices
    char* wbase = smem + wave * 6144;            // 3 bufs x 2048 B per wave

    const int cached = (count <= 512);           // always true for uniform labels
    const int cmax   = cached ? count : 512;
    for (int r = threadIdx.x; r < cmax; r += 512) ids[r] = sorted[start + r];
    __syncthreads();

    // staging-side (source) swizzle: lane l holds row/chunk s' = l ^ (l>>3)
    const int sprime = (lane ^ (lane >> 3)) & 63;
    const int srow   = sprime & 3;
    const int schunk = sprime >> 2;
    // consume-side swizzled slot for (g, sub)
    const int sidx = (sub << 2) | g;
    const int t1   = sidx ^ (sidx >> 3);

    float4 aLo = make_float4(0.f, 0.f, 0.f, 0.f);
    float4 aHi = make_float4(0.f, 0.f, 0.f, 0.f);

    if (count > 0) {
        const int nb = (count + 3) >> 2;                 // total 4-row batches
        const int Kw = (nb > wave) ? ((nb - 1 - wave) / WPB + 1) : 0;
        // prologue: batches w, w+8, w+16 -> bufs 0,1,2 (dummies clamp to row 0)
        stage_batch(emb, ids, sorted, cached, start, wave,           count, srow, schunk, wbase);
        stage_batch(emb, ids, sorted, cached, start, wave + WPB,     count, srow, schunk, wbase + 2048);
        stage_batch(emb, ids, sorted, cached, start, wave + 2 * WPB, count, srow, schunk, wbase + 4096);
        for (int k = 0; k < Kw; ++k) {
            asm volatile("s_waitcnt vmcnt(4)" ::: "memory");  // batch k landed
            __builtin_amdgcn_sched_barrier(0);
            const float4* buf = (const float4*)(wbase + (k % 3) * 2048);
            float4 a0 = buf[t1];                 // chunk sub    of row g
            float4 a1 = buf[64 + t1];            // chunk sub+16 of row g
            asm volatile("s_waitcnt lgkmcnt(0)" ::: "memory");  // reads done
            __builtin_amdgcn_sched_barrier(0);
            // re-stage this buffer with batch k+3 (WAR-safe: reads complete)
            stage_batch(emb, ids, sorted, cached, start,
                        wave + (k + 3) * WPB, count, srow, schunk,
                        wbase + (k % 3) * 2048);
            const int rid = ((wave + k * WPB) << 2) + g;
            float sq  = red16(sumsq8(a0, a1));   // 16-lane row reduce
            float inv = ((rid < count) ? 1.0f : 0.0f) / fmaxf(sqrtf(sq), 1e-12f);
            aLo.x += a0.x * inv; aLo.y += a0.y * inv; aLo.z += a0.z * inv; aLo.w += a0.w * inv;
            aHi.x += a1.x * inv; aHi.y += a1.y * inv; aHi.z += a1.z * inv; aHi.w += a1.w * inv;
        }
    }
    asm volatile("s_waitcnt vmcnt(0)" ::: "memory");  // drain pending DMA
    __syncthreads();                                  // before scratch reuse

    // Reduce 32 partial vectors (8 waves x 4 groups) of 128 dims.
    float (*sred)[16][8] = (float (*)[16][8])smem;    // 16 KB (reuses staging)
    {
        float* dst = sred[wave * 4 + g][sub];
        dst[0] = aLo.x; dst[1] = aLo.y; dst[2] = aLo.z; dst[3] = aLo.w;
        dst[4] = aHi.x; dst[5] = aHi.y; dst[6] = aHi.z; dst[7] = aHi.w;
    }
    __syncthreads();

    float* red = (float*)(smem + 16384);
    if (threadIdx.x < 128) {
        const int d  = threadIdx.x;
        const int dd = d & 63;
        const int sb = dd >> 2;
        const int j  = (d >> 6) * 4 + (dd & 3);
        float tt = 0.0f;
        #pragma unroll
        for (int k = 0; k < WPB * 4; k++) tt += sred[k][sb][j];
        red[d] = tt * tt;
    }
    __syncthreads();
    if (threadIdx.x < 64) {
        float x = red[threadIdx.x] + red[threadIdx.x + 64];
        #pragma unroll
        for (int off = 32; off; off >>= 1) x += __shfl_xor(x, off, 64);
        if (threadIdx.x == 0) {
            if (count >= 2) {
                float nrm = sqrtf(x);                   // = sum over class of sim
                float per_class = ((float)count - nrm) / (float)count;
                atomicAdd(&accum[0], per_class);
                atomicAdd(&accum[1], 1.0f);
            }
            __threadfence();
            int old = atomicAdd(ticket, 1);
            if (old == NUM_CLASSES - 1) {
                // device-scope atomic reads (cross-XCD safe)
                float ls = atomicAdd(&accum[0], 0.0f);
                float nv = atomicAdd(&accum[1], 0.0f);
                out[0] = (nv > 0.0f) ? (ls / nv) : 0.0f;
            }
        }
    }
}

extern "C" void kernel_launch(void* const* d_in, const int* in_sizes, int n_in,
                              void* d_out, int out_size, void* d_ws, size_t ws_size,
                              hipStream_t stream) {
    const float* emb  = (const float*)d_in[0];   // fp32, N x 128
    const int* labels = (const int*)d_in[1];     // int32 (int64 handled inline)
    const int n = in_sizes[1];                   // 262144 samples

    // Workspace layout (~1.55 MB). pT follows sorted and doubles as read pad.
    char* ws = (char*)d_ws;
    int*   counts  = (int*)(ws + 0);                       // 1024 ints
    int*   offsets = (int*)(ws + 4096);                    // 1024 ints
    int*   totals  = (int*)(ws + 8192);                    // 1024 ints
    float* accum   = (float*)(ws + 12288);                 // 2 floats
    int*   ticket  = (int*)(ws + 12304);                   // 1 int
    int*   sorted  = (int*)(ws + 16384);                   // n ints (1 MB)
    int*   pT      = (int*)(ws + 16384 + (size_t)n * 4);   // C*NB ints (512 KB)

    hist_kernel <<<NB, 256, 0, stream>>>(labels, n, pT);
    scanA_kernel<<<NB, 512, 0, stream>>>(pT, totals);
    scanB_kernel<<<1, NUM_CLASSES, 0, stream>>>(totals, offsets, counts, accum, ticket);
    scatter_kernel<<<NB, 256, 0, stream>>>(labels, n, pT, offsets, sorted);
    class_sum_kernel<<<NUM_CLASSES, 512, 0, stream>>>(emb, sorted, offsets, counts,
                                                      accum, ticket, (float*)d_out);
}